// Round 1
// baseline (534.716 us; speedup 1.0000x reference)
//
#include <hip/hip_runtime.h>
#include <hip/hip_bf16.h>
#include <stdint.h>

// LightAttention: out = x + gamma * softmax((x Wq^T)(x Wk^T)^T / sqrt(D)) @ x
// B=4, T=4096, D=512, fp32 in/out. bf16 MFMA pipeline (threshold is bf16-grade).

#define B_ 4
#define T_ 4096
#define D_ 512
#define M_ (B_*T_)   // 16384

typedef short short8 __attribute__((ext_vector_type(8)));   // 8 bf16 in 4 VGPRs
typedef float f32x4 __attribute__((ext_vector_type(4)));

__device__ __forceinline__ unsigned short f2bf(float x) {
  union { float f; unsigned u; } v; v.f = x;
  unsigned r = v.u + 0x7fffu + ((v.u >> 16) & 1u);   // RNE
  return (unsigned short)(r >> 16);
}

__device__ __forceinline__ void gload_lds16(const void* g, void* l) {
  __builtin_amdgcn_global_load_lds((const __attribute__((address_space(1))) void*)g,
                                   (__attribute__((address_space(3))) void*)l, 16, 0, 0);
}

// ---------------- kernel 1: Wq/Wk fp32 -> bf16 ----------------
__global__ __launch_bounds__(256) void cvt_w(const float* __restrict__ wq,
                                             const float* __restrict__ wk,
                                             unsigned short* __restrict__ oq,
                                             unsigned short* __restrict__ ok) {
  int i = (blockIdx.x * 256 + threadIdx.x) * 4;   // 512 blocks -> 524288 = 2*512*512
  const float* s; unsigned short* d;
  if (i < 262144) { s = wq + i; d = oq + i; }
  else            { s = wk + (i - 262144); d = ok + (i - 262144); }
  float4 v = *(const float4*)s;
  ushort4 h; h.x = f2bf(v.x); h.y = f2bf(v.y); h.z = f2bf(v.z); h.w = f2bf(v.w);
  *(ushort4*)d = h;
}

// ---------------- kernel 2: x -> xb (bf16 row-major) + xT (bf16 [B][D][T]) ----------------
__global__ __launch_bounds__(256) void prep_x(const float* __restrict__ x,
                                              unsigned short* __restrict__ xb,
                                              unsigned short* __restrict__ xT) {
  __shared__ unsigned short ldsT[64][72];   // [d][t], padded stride
  int wg = blockIdx.x;                 // 2048 = 4 * (4096/64) * (512/64)
  int b = wg >> 9;
  int rem = wg & 511;
  int tt = rem >> 3, dt = rem & 7;
  int t0 = tt * 64, d0 = dt * 64;
  int tid = threadIdx.x;
  int p = tid & 15, rw = tid >> 4;
#pragma unroll
  for (int k = 0; k < 4; ++k) {
    int tr = rw + 16 * k;
    size_t off = ((size_t)(b * 4096 + t0 + tr)) * 512 + d0 + p * 4;
    float4 v = *(const float4*)(x + off);
    ushort4 h; h.x = f2bf(v.x); h.y = f2bf(v.y); h.z = f2bf(v.z); h.w = f2bf(v.w);
    *(ushort4*)(xb + off) = h;
    ldsT[p * 4 + 0][tr] = h.x; ldsT[p * 4 + 1][tr] = h.y;
    ldsT[p * 4 + 2][tr] = h.z; ldsT[p * 4 + 3][tr] = h.w;
  }
  __syncthreads();
#pragma unroll
  for (int k = 0; k < 4; ++k) {
    int dr = rw + 16 * k;
    ushort4 h;
    h.x = ldsT[dr][p * 4 + 0]; h.y = ldsT[dr][p * 4 + 1];
    h.z = ldsT[dr][p * 4 + 2]; h.w = ldsT[dr][p * 4 + 3];
    *(ushort4*)(xT + (size_t)b * 512 * 4096 + (size_t)(d0 + dr) * 4096 + t0 + p * 4) = h;
  }
}

// ---------------- kernel 3: Q/K projection GEMM (128x128x64, bf16 MFMA) ----------------
// C[m,n] = sum_k xb[m,k] * W[n,k] (+bias[n]) * sc ; z=0 -> Q (scaled 1/sqrt(D)), z=1 -> K
__global__ __launch_bounds__(256, 2) void proj_gemm(const unsigned short* __restrict__ A,
                                                    const unsigned short* __restrict__ wq,
                                                    const unsigned short* __restrict__ wk,
                                                    const float* __restrict__ bq,
                                                    const float* __restrict__ bk,
                                                    unsigned short* __restrict__ Qo,
                                                    unsigned short* __restrict__ Ko,
                                                    float qscale) {
  __shared__ unsigned short As[2][8192];   // [128][64] bf16, XOR-swizzled chunks
  __shared__ unsigned short Bs[2][8192];
  const int tid = threadIdx.x;
  const int mt = blockIdx.x, nt = blockIdx.y, qk = blockIdx.z;
  const unsigned short* W = qk ? wk : wq;
  const float* bias = qk ? bk : bq;
  unsigned short* out = qk ? Ko : Qo;
  const float sc = qk ? 1.0f : qscale;
  const int m0 = mt * 128, n0 = nt * 128;
  const int l = tid & 63, q15 = l & 15, g = l >> 4;
  const int w = tid >> 6, wm = w >> 1, wn = w & 1;

  // pre-swizzled global source so linear global_load_lds lands XOR-swizzled (rule 21)
  auto stage = [&](int buf, int k0) {
#pragma unroll
    for (int j = 0; j < 4; ++j) {
      int chunk = j * 256 + tid;           // 1024 x 16B chunks per 16KB tile
      int row = chunk >> 3, cc = chunk & 7;
      int ccs = cc ^ (row & 7);
      gload_lds16(A + (size_t)(m0 + row) * 512 + k0 + ccs * 8, &As[buf][chunk * 8]);
      gload_lds16(W + (size_t)(n0 + row) * 512 + k0 + ccs * 8, &Bs[buf][chunk * 8]);
    }
  };
  stage(0, 0);
  asm volatile("s_waitcnt vmcnt(0)" ::: "memory");
  __syncthreads();

  f32x4 acc[4][4] = {};
  for (int kt = 0; kt < 8; ++kt) {
    int cur = kt & 1;
    if (kt < 7) stage(cur ^ 1, (kt + 1) * 64);
#pragma unroll
    for (int ks = 0; ks < 2; ++ks) {
      short8 av[4], bv[4];
#pragma unroll
      for (int mf = 0; mf < 4; ++mf) {
        int row = 64 * wm + 16 * mf + q15;
        int cb = (ks * 64 + g * 16) ^ ((row & 7) << 4);
        av[mf] = *(const short8*)((const char*)&As[cur][0] + row * 128 + cb);
      }
#pragma unroll
      for (int nf = 0; nf < 4; ++nf) {
        int row = 64 * wn + 16 * nf + q15;
        int cb = (ks * 64 + g * 16) ^ ((row & 7) << 4);
        bv[nf] = *(const short8*)((const char*)&Bs[cur][0] + row * 128 + cb);
      }
#pragma unroll
      for (int mf = 0; mf < 4; ++mf)
#pragma unroll
        for (int nf = 0; nf < 4; ++nf)
          acc[mf][nf] = __builtin_amdgcn_mfma_f32_16x16x32_bf16(av[mf], bv[nf], acc[mf][nf], 0, 0, 0);
    }
    asm volatile("s_waitcnt vmcnt(0)" ::: "memory");
    __syncthreads();
  }
#pragma unroll
  for (int nf = 0; nf < 4; ++nf) {
    int n = n0 + 64 * wn + 16 * nf + q15;
    float bv = bias[n];
#pragma unroll
    for (int mf = 0; mf < 4; ++mf) {
      int mbase = m0 + 64 * wm + 16 * mf + 4 * g;
#pragma unroll
      for (int r = 0; r < 4; ++r)
        out[(size_t)(mbase + r) * 512 + n] = f2bf((acc[mf][nf][r] + bv) * sc);
    }
  }
}

// ---------------- kernel 4: fused flash attention + residual ----------------
// 1 WG = 64 q-rows; 4 waves: QK wave w owns q 16w..16w+15 (Q frags in regs, swapped
// mfma(K,Q) -> S^T so softmax is per-lane); PV wave w owns dout 128w..128w+127.
__global__ __launch_bounds__(256, 1) void attn_kernel(const unsigned short* __restrict__ Qb,
                                                      const unsigned short* __restrict__ Kb,
                                                      const unsigned short* __restrict__ xT,
                                                      const float* __restrict__ x,
                                                      const float* __restrict__ gmp,
                                                      float* __restrict__ out) {
  extern __shared__ char smem[];
  unsigned short* Kbuf = (unsigned short*)smem;              // 2 x [64][512] bf16 (XOR swz)
  unsigned short* Pl   = (unsigned short*)(smem + 131072);   // [64][72] bf16
  float* scale_lds = (float*)(smem + 140288);                // [64]
  float* lsum_lds  = (float*)(smem + 140544);                // [64]

  const int hw = blockIdx.x;
  const int wg = (hw & 7) * 32 + (hw >> 3);   // XCD-chunked swizzle (256 % 8 == 0)
  const int b = wg >> 6, qt = wg & 63;
  const int tid = threadIdx.x;
  const int w = tid >> 6, l = tid & 63, q15 = l & 15, g = l >> 4;

  // Q B-fragments: Q[qt*64+16w+q15][32*ds + 8g + e], held for entire kernel
  short8 qf_[16];
  {
    const unsigned short* Qrow = Qb + ((size_t)(b * 4096 + qt * 64 + 16 * w + q15)) * 512 + g * 8;
#pragma unroll
    for (int ds = 0; ds < 16; ++ds) qf_[ds] = *(const short8*)(Qrow + ds * 32);
  }
  const unsigned short* KbB = Kb + (size_t)b * 4096 * 512;
  const unsigned short* xTb = xT + (size_t)b * 512 * 4096;

  // K tile staging: 256 threads x 2 rows x 8 chunks = 64 rows x 1KB
  short8 kst[2][8];
  const int krow = tid >> 3, kcc = tid & 7;
  auto k_load = [&](int kt) {
#pragma unroll
    for (int h = 0; h < 2; ++h) {
      const unsigned short* src = KbB + (size_t)(kt * 64 + krow + 32 * h) * 512 + kcc * 64;
#pragma unroll
      for (int k = 0; k < 8; ++k) kst[h][k] = *(const short8*)(src + k * 8);
    }
  };
  auto k_store = [&](int buf) {
#pragma unroll
    for (int h = 0; h < 2; ++h) {
      int row = krow + 32 * h;
      char* dst = (char*)(Kbuf + buf * 32768) + row * 1024;
#pragma unroll
      for (int k = 0; k < 8; ++k) {
        int cb = (kcc * 128 + k * 16) ^ ((row & 7) << 4);
        *(short8*)(dst + cb) = kst[h][k];
      }
    }
  };

  f32x4 Oacc[4][8] = {};
  float mrun = -1e30f, lsum = 0.f;

  k_load(0); k_store(0);
  __syncthreads();

#pragma unroll 1
  for (int kt = 0; kt < 64; ++kt) {
    const int cur = kt & 1;
    if (kt < 63) k_load(kt + 1);                 // prefetch next K tile into regs
    // V B-frags for current tile straight from L2 (read exactly once per WG)
    short8 vf[8][2];
#pragma unroll
    for (int f = 0; f < 8; ++f)
#pragma unroll
      for (int ks = 0; ks < 2; ++ks)
        vf[f][ks] = *(const short8*)(xTb + (size_t)(128 * w + 16 * f + q15) * 4096
                                     + kt * 64 + ks * 32 + g * 8);
    // QK^T (swapped): S^T[kv][q], frag n covers kv 16n..16n+15
    f32x4 Sacc[4] = {};
    const char* kb = (const char*)(Kbuf + cur * 32768);
#pragma unroll
    for (int ds = 0; ds < 16; ++ds) {
#pragma unroll
      for (int n = 0; n < 4; ++n) {
        int row = 16 * n + q15;
        int cb = (ds * 64 + g * 16) ^ ((row & 7) << 4);
        short8 kf = *(const short8*)(kb + row * 1024 + cb);
        Sacc[n] = __builtin_amdgcn_mfma_f32_16x16x32_bf16(kf, qf_[ds], Sacc[n], 0, 0, 0);
      }
    }
    // online softmax: lane owns q = 16w+q15; its 16 values are kv = 16n + 4g + r
    float pmax = -1e30f;
#pragma unroll
    for (int n = 0; n < 4; ++n)
#pragma unroll
      for (int r = 0; r < 4; ++r) pmax = fmaxf(pmax, Sacc[n][r]);
    pmax = fmaxf(pmax, __shfl_xor(pmax, 16, 64));
    pmax = fmaxf(pmax, __shfl_xor(pmax, 32, 64));
    const float mnew = fmaxf(mrun, pmax);
    const float scl = __expf(mrun - mnew);
    float psum = 0.f;
    unsigned short* pr = Pl + (16 * w + q15) * 72 + 4 * g;
#pragma unroll
    for (int n = 0; n < 4; ++n)
#pragma unroll
      for (int r = 0; r < 4; ++r) {
        float p = __expf(Sacc[n][r] - mnew);
        psum += p;
        pr[16 * n + r] = f2bf(p);
      }
    psum += __shfl_xor(psum, 16, 64);
    psum += __shfl_xor(psum, 32, 64);
    lsum = lsum * scl + psum;
    mrun = mnew;
    if (g == 0) scale_lds[16 * w + q15] = scl;
    if (kt < 63) k_store(cur ^ 1);               // write next K tile (other buffer)
    __syncthreads();
    // PV: wave owns dout quarter; rescale O then accumulate P@V
#pragma unroll
    for (int qf = 0; qf < 4; ++qf) {
      float s0 = scale_lds[16 * qf + 4 * g + 0];
      float s1 = scale_lds[16 * qf + 4 * g + 1];
      float s2 = scale_lds[16 * qf + 4 * g + 2];
      float s3 = scale_lds[16 * qf + 4 * g + 3];
      const char* prow = (const char*)Pl + (16 * qf + q15) * 144 + g * 16;
      short8 pa0 = *(const short8*)(prow);
      short8 pa1 = *(const short8*)(prow + 64);
#pragma unroll
      for (int f = 0; f < 8; ++f) {
        f32x4 a = Oacc[qf][f];
        a[0] *= s0; a[1] *= s1; a[2] *= s2; a[3] *= s3;
        a = __builtin_amdgcn_mfma_f32_16x16x32_bf16(pa0, vf[f][0], a, 0, 0, 0);
        a = __builtin_amdgcn_mfma_f32_16x16x32_bf16(pa1, vf[f][1], a, 0, 0, 0);
        Oacc[qf][f] = a;
      }
    }
    __syncthreads();
  }
  if (g == 0) lsum_lds[16 * w + q15] = lsum;
  __syncthreads();
  const float gam = gmp[0];
#pragma unroll
  for (int qf = 0; qf < 4; ++qf) {
    float li0 = 1.f / lsum_lds[16 * qf + 4 * g + 0];
    float li1 = 1.f / lsum_lds[16 * qf + 4 * g + 1];
    float li2 = 1.f / lsum_lds[16 * qf + 4 * g + 2];
    float li3 = 1.f / lsum_lds[16 * qf + 4 * g + 3];
#pragma unroll
    for (int f = 0; f < 8; ++f) {
      int d = 128 * w + 16 * f + q15;
      size_t base = ((size_t)(b * 4096 + qt * 64 + 16 * qf + 4 * g)) * 512 + d;
      f32x4 a = Oacc[qf][f];
      out[base]        = x[base]        + gam * a[0] * li0;
      out[base + 512]  = x[base + 512]  + gam * a[1] * li1;
      out[base + 1024] = x[base + 1024] + gam * a[2] * li2;
      out[base + 1536] = x[base + 1536] + gam * a[3] * li3;
    }
  }
}

// ---------------- launch ----------------
extern "C" void kernel_launch(void* const* d_in, const int* in_sizes, int n_in,
                              void* d_out, int out_size, void* d_ws, size_t ws_size,
                              hipStream_t stream) {
  (void)in_sizes; (void)n_in; (void)out_size; (void)ws_size;
  const float* x  = (const float*)d_in[0];
  const float* Wq = (const float*)d_in[1];
  const float* bq = (const float*)d_in[2];
  const float* Wk = (const float*)d_in[3];
  const float* bk = (const float*)d_in[4];
  const float* gm = (const float*)d_in[5];
  float* out = (float*)d_out;

  char* ws = (char*)d_ws;   // needs ~68.2 MB
  unsigned short* Qb  = (unsigned short*)(ws);                // 16384*512 bf16
  unsigned short* Kb  = (unsigned short*)(ws + 16777216);     // 16384*512 bf16
  unsigned short* xT  = (unsigned short*)(ws + 33554432);     // 4*512*4096 bf16
  unsigned short* xb  = (unsigned short*)(ws + 50331648);     // 16384*512 bf16
  unsigned short* Wqb = (unsigned short*)(ws + 67108864);     // 512*512 bf16
  unsigned short* Wkb = (unsigned short*)(ws + 67633152);     // 512*512 bf16

  hipFuncSetAttribute((const void*)attn_kernel,
                      hipFuncAttributeMaxDynamicSharedMemorySize, 140800);

  cvt_w<<<512, 256, 0, stream>>>(Wq, Wk, Wqb, Wkb);
  prep_x<<<2048, 256, 0, stream>>>(x, xb, xT);
  proj_gemm<<<dim3(128, 4, 2), 256, 0, stream>>>(xb, Wqb, Wkb, bq, bk, Qb, Kb,
                                                 0.04419417382415922f);
  attn_kernel<<<256, 256, 140800, stream>>>(Qb, Kb, xT, x, gm, out);
}

// Round 3
// 264.239 us; speedup vs baseline: 2.0236x; 2.0236x over previous
//
#include <hip/hip_runtime.h>
#include <hip/hip_bf16.h>
#include <stdint.h>

// LightAttention: out = x + gamma * softmax((x Wq^T)(x Wk^T)^T / sqrt(D)) @ x
// B=4, T=4096, D=512, fp32 in/out. bf16 MFMA pipeline (threshold is bf16-grade).

#define B_ 4
#define T_ 4096
#define D_ 512

typedef short short8 __attribute__((ext_vector_type(8)));   // 8 bf16 in 4 VGPRs
typedef float f32x4 __attribute__((ext_vector_type(4)));

__device__ __forceinline__ unsigned short f2bf(float x) {
  union { float f; unsigned u; } v; v.f = x;
  unsigned r = v.u + 0x7fffu + ((v.u >> 16) & 1u);   // RNE
  return (unsigned short)(r >> 16);
}

__device__ __forceinline__ void gload_lds16(const void* g, void* l) {
  __builtin_amdgcn_global_load_lds((const __attribute__((address_space(1))) void*)g,
                                   (__attribute__((address_space(3))) void*)l, 16, 0, 0);
}

// ---------------- kernel 1: Wq/Wk fp32 -> bf16 ----------------
__global__ __launch_bounds__(256) void cvt_w(const float* __restrict__ wq,
                                             const float* __restrict__ wk,
                                             unsigned short* __restrict__ oq,
                                             unsigned short* __restrict__ ok) {
  int i = (blockIdx.x * 256 + threadIdx.x) * 4;
  const float* s; unsigned short* d;
  if (i < 262144) { s = wq + i; d = oq + i; }
  else            { s = wk + (i - 262144); d = ok + (i - 262144); }
  float4 v = *(const float4*)s;
  ushort4 h; h.x = f2bf(v.x); h.y = f2bf(v.y); h.z = f2bf(v.z); h.w = f2bf(v.w);
  *(ushort4*)d = h;
}

// ---------------- kernel 2: x -> xb (bf16 row-major) + xT (bf16 [B][D][T]) ----------------
__global__ __launch_bounds__(256) void prep_x(const float* __restrict__ x,
                                              unsigned short* __restrict__ xb,
                                              unsigned short* __restrict__ xT) {
  __shared__ unsigned short ldsT[64][72];
  int wg = blockIdx.x;                 // 2048 = 4 * (4096/64) * (512/64)
  int b = wg >> 9;
  int rem = wg & 511;
  int tt = rem >> 3, dt = rem & 7;
  int t0 = tt * 64, d0 = dt * 64;
  int tid = threadIdx.x;
  int p = tid & 15, rw = tid >> 4;
#pragma unroll
  for (int k = 0; k < 4; ++k) {
    int tr = rw + 16 * k;
    size_t off = ((size_t)(b * 4096 + t0 + tr)) * 512 + d0 + p * 4;
    float4 v = *(const float4*)(x + off);
    ushort4 h; h.x = f2bf(v.x); h.y = f2bf(v.y); h.z = f2bf(v.z); h.w = f2bf(v.w);
    *(ushort4*)(xb + off) = h;
    ldsT[p * 4 + 0][tr] = h.x; ldsT[p * 4 + 1][tr] = h.y;
    ldsT[p * 4 + 2][tr] = h.z; ldsT[p * 4 + 3][tr] = h.w;
  }
  __syncthreads();
#pragma unroll
  for (int k = 0; k < 4; ++k) {
    int dr = rw + 16 * k;
    ushort4 h;
    h.x = ldsT[dr][p * 4 + 0]; h.y = ldsT[dr][p * 4 + 1];
    h.z = ldsT[dr][p * 4 + 2]; h.w = ldsT[dr][p * 4 + 3];
    *(ushort4*)(xT + (size_t)b * 512 * 4096 + (size_t)(d0 + dr) * 4096 + t0 + p * 4) = h;
  }
}

// ---------------- kernel 3: Q/K projection GEMM (128x128x64, bf16 MFMA) ----------------
__global__ __launch_bounds__(256, 2) void proj_gemm(const unsigned short* __restrict__ A,
                                                    const unsigned short* __restrict__ wq,
                                                    const unsigned short* __restrict__ wk,
                                                    const float* __restrict__ bq,
                                                    const float* __restrict__ bk,
                                                    unsigned short* __restrict__ Qo,
                                                    unsigned short* __restrict__ Ko,
                                                    float qscale) {
  __shared__ unsigned short As[2][8192];
  __shared__ unsigned short Bs[2][8192];
  const int tid = threadIdx.x;
  const int mt = blockIdx.x, nt = blockIdx.y, qk = blockIdx.z;
  const unsigned short* W = qk ? wk : wq;
  const float* bias = qk ? bk : bq;
  unsigned short* out = qk ? Ko : Qo;
  const float sc = qk ? 1.0f : qscale;
  const int m0 = mt * 128, n0 = nt * 128;
  const int l = tid & 63, q15 = l & 15, g = l >> 4;
  const int w = tid >> 6, wm = w >> 1, wn = w & 1;

  auto stage = [&](int buf, int k0) {
#pragma unroll
    for (int j = 0; j < 4; ++j) {
      int chunk = j * 256 + tid;
      int row = chunk >> 3, cc = chunk & 7;
      int ccs = cc ^ (row & 7);
      gload_lds16(A + (size_t)(m0 + row) * 512 + k0 + ccs * 8, &As[buf][chunk * 8]);
      gload_lds16(W + (size_t)(n0 + row) * 512 + k0 + ccs * 8, &Bs[buf][chunk * 8]);
    }
  };
  stage(0, 0);
  __syncthreads();

  f32x4 acc[4][4] = {};
  for (int kt = 0; kt < 8; ++kt) {
    int cur = kt & 1;
    if (kt < 7) stage(cur ^ 1, (kt + 1) * 64);
#pragma unroll
    for (int ks = 0; ks < 2; ++ks) {
      short8 av[4], bv[4];
#pragma unroll
      for (int mf = 0; mf < 4; ++mf) {
        int row = 64 * wm + 16 * mf + q15;
        int cb = (ks * 64 + g * 16) ^ ((row & 7) << 4);
        av[mf] = *(const short8*)((const char*)&As[cur][0] + row * 128 + cb);
      }
#pragma unroll
      for (int nf = 0; nf < 4; ++nf) {
        int row = 64 * wn + 16 * nf + q15;
        int cb = (ks * 64 + g * 16) ^ ((row & 7) << 4);
        bv[nf] = *(const short8*)((const char*)&Bs[cur][0] + row * 128 + cb);
      }
#pragma unroll
      for (int mf = 0; mf < 4; ++mf)
#pragma unroll
        for (int nf = 0; nf < 4; ++nf)
          acc[mf][nf] = __builtin_amdgcn_mfma_f32_16x16x32_bf16(av[mf], bv[nf], acc[mf][nf], 0, 0, 0);
    }
    __syncthreads();
  }
#pragma unroll
  for (int nf = 0; nf < 4; ++nf) {
    int n = n0 + 64 * wn + 16 * nf + q15;
    float bv = bias[n];
#pragma unroll
    for (int mf = 0; mf < 4; ++mf) {
      int mbase = m0 + 64 * wm + 16 * mf + 4 * g;
#pragma unroll
      for (int r = 0; r < 4; ++r)
        out[(size_t)(mbase + r) * 512 + n] = f2bf((acc[mf][nf][r] + bv) * sc);
    }
  }
}

// ---------------- kernel 4: fused flash attention + residual ----------------
// 512 threads = 8 waves, wave-specialized software pipeline:
//   waves 0-3 (QK):  wave w owns q 16w..16w+15. Q frags in regs; swapped
//                    mfma(K,Q) -> S^T; per-lane online softmax; writes P+scale.
//   waves 4-7 (PV):  wave pw owns dout d-quarter 128pw..128pw+127; consumes
//                    P/scale of the PREVIOUS tile (1-slot skew) + V from L2.
// K staged via global_load_lds (pre-swizzled source), double-buffered.
// ALL synchronization is __syncthreads() (full drain) -- one per slot.
__global__ __launch_bounds__(512) void attn_kernel(const unsigned short* __restrict__ Qb,
                                                   const unsigned short* __restrict__ Kb,
                                                   const unsigned short* __restrict__ xT,
                                                   const float* __restrict__ x,
                                                   const float* __restrict__ gmp,
                                                   float* __restrict__ out) {
  extern __shared__ char smem[];
  // [0, 131072)      : Kbuf 2 x [64 rows][1024 B], XOR-swizzled 16B chunks
  // [131072, 149504) : P    2 x [64 q][72 kv] bf16
  // [149504, 150016) : scale 2 x [64] f32
  // [150016, 150272) : lsum [64] f32
  unsigned short* Pl = (unsigned short*)(smem + 131072);
  float* scale_lds = (float*)(smem + 149504);
  float* lsum_lds  = (float*)(smem + 150016);

  const int hw = blockIdx.x;
  const int wg = (hw & 7) * 32 + (hw >> 3);   // XCD-chunked swizzle (256 % 8 == 0)
  const int b = wg >> 6, qt = wg & 63;
  const int tid = threadIdx.x;
  const int w = tid >> 6, l = tid & 63, q15 = l & 15, g = l >> 4;

  const unsigned short* KbB = Kb + (size_t)b * 4096 * 512;
  const unsigned short* xTb = xT + (size_t)b * 512 * 4096;

  // stage K tile kt into Kbuf[buf]: linear LDS dest, inverse-swizzled global src.
  // final LDS layout: row r, 16B-chunk c holds K[r][(c ^ (r&7))*8 ..+8)
  // 512 threads x 8 chunks = 4096 chunks (64 rows x 1KB)
  auto stage = [&](int buf, int kt) {
    const unsigned short* src = KbB + (size_t)kt * 64 * 512;
    char* dst = smem + buf * 65536;
#pragma unroll
    for (int j = 0; j < 8; ++j) {
      int ch = j * 512 + tid;
      int r = ch >> 6, c = ch & 63;
      gload_lds16(src + (size_t)r * 512 + ((c ^ (r & 7)) << 3), dst + ch * 16);
    }
  };

  stage(0, 0);
  __syncthreads();

  if (w < 4) {
    // ================= QK + softmax waves =================
    short8 qf_[16];
    {
      const unsigned short* Qrow = Qb + ((size_t)(b * 4096 + qt * 64 + 16 * w + q15)) * 512 + g * 8;
#pragma unroll
      for (int ds = 0; ds < 16; ++ds) qf_[ds] = *(const short8*)(Qrow + ds * 32);
    }
    float mrun = -1e30f, lsum = 0.f;

#pragma unroll 1
    for (int s = 0; s <= 64; ++s) {
      if (s < 63) stage((s + 1) & 1, s + 1);
      if (s < 64) {
        const int cur = s & 1;
        // QK^T (swapped): S^T[kv][q], frag n covers kv 16n..16n+15
        f32x4 Sacc[4] = {};
        const char* kb = smem + cur * 65536;
#pragma unroll
        for (int ds = 0; ds < 16; ++ds) {
#pragma unroll
          for (int n = 0; n < 4; ++n) {
            int row = 16 * n + q15;
            int cb = ((4 * ds + g) ^ (row & 7)) << 4;
            short8 kf = *(const short8*)(kb + row * 1024 + cb);
            Sacc[n] = __builtin_amdgcn_mfma_f32_16x16x32_bf16(kf, qf_[ds], Sacc[n], 0, 0, 0);
          }
        }
        // online softmax: lane owns q = 16w+q15; values kv = 16n + 4g + r
        float pmax = -1e30f;
#pragma unroll
        for (int n = 0; n < 4; ++n)
#pragma unroll
          for (int r = 0; r < 4; ++r) pmax = fmaxf(pmax, Sacc[n][r]);
        pmax = fmaxf(pmax, __shfl_xor(pmax, 16, 64));
        pmax = fmaxf(pmax, __shfl_xor(pmax, 32, 64));
        const float mnew = fmaxf(mrun, pmax);
        const float scl = __expf(mrun - mnew);
        float psum = 0.f;
        unsigned short* Pp = Pl + cur * 4608 + (16 * w + q15) * 72;
#pragma unroll
        for (int n = 0; n < 4; ++n) {
          ushort4 pk;
          float p0 = __expf(Sacc[n][0] - mnew); psum += p0; pk.x = f2bf(p0);
          float p1 = __expf(Sacc[n][1] - mnew); psum += p1; pk.y = f2bf(p1);
          float p2 = __expf(Sacc[n][2] - mnew); psum += p2; pk.z = f2bf(p2);
          float p3 = __expf(Sacc[n][3] - mnew); psum += p3; pk.w = f2bf(p3);
          *(ushort4*)(Pp + 16 * n + 4 * g) = pk;
        }
        psum += __shfl_xor(psum, 16, 64);
        psum += __shfl_xor(psum, 32, 64);
        lsum = lsum * scl + psum;
        mrun = mnew;
        if (g == 0) scale_lds[cur * 64 + 16 * w + q15] = scl;
        if (s == 63 && g == 0) lsum_lds[16 * w + q15] = lsum;
      }
      __syncthreads();
    }
  } else {
    // ================= PV + rescale waves =================
    const int pw = w - 4;
    f32x4 Oacc[4][8] = {};

#pragma unroll 1
    for (int s = 0; s <= 64; ++s) {
      if (s < 63) stage((s + 1) & 1, s + 1);
      if (s >= 1) {
        const int tv = s - 1;           // tile consumed this slot
        const int cur = tv & 1;
        // V B-frags straight from L2 (read once per WG)
        short8 vf[8][2];
#pragma unroll
        for (int f = 0; f < 8; ++f)
#pragma unroll
          for (int ks = 0; ks < 2; ++ks)
            vf[f][ks] = *(const short8*)(xTb + (size_t)(128 * pw + 16 * f + q15) * 4096
                                         + tv * 64 + ks * 32 + g * 8);
        const float* scp = scale_lds + cur * 64;
#pragma unroll
        for (int qf = 0; qf < 4; ++qf) {
          float s0 = scp[16 * qf + 4 * g + 0];
          float s1 = scp[16 * qf + 4 * g + 1];
          float s2 = scp[16 * qf + 4 * g + 2];
          float s3 = scp[16 * qf + 4 * g + 3];
          const char* prow = (const char*)(Pl + cur * 4608) + (16 * qf + q15) * 144 + g * 16;
          short8 pa0 = *(const short8*)(prow);
          short8 pa1 = *(const short8*)(prow + 64);
#pragma unroll
          for (int f = 0; f < 8; ++f) {
            f32x4 a = Oacc[qf][f];
            a[0] *= s0; a[1] *= s1; a[2] *= s2; a[3] *= s3;
            a = __builtin_amdgcn_mfma_f32_16x16x32_bf16(pa0, vf[f][0], a, 0, 0, 0);
            a = __builtin_amdgcn_mfma_f32_16x16x32_bf16(pa1, vf[f][1], a, 0, 0, 0);
            Oacc[qf][f] = a;
          }
        }
      }
      __syncthreads();
    }

    // epilogue: PV waves write out (they hold Oacc)
    const float gam = gmp[0];
#pragma unroll
    for (int qf = 0; qf < 4; ++qf) {
      float li0 = 1.f / lsum_lds[16 * qf + 4 * g + 0];
      float li1 = 1.f / lsum_lds[16 * qf + 4 * g + 1];
      float li2 = 1.f / lsum_lds[16 * qf + 4 * g + 2];
      float li3 = 1.f / lsum_lds[16 * qf + 4 * g + 3];
#pragma unroll
      for (int f = 0; f < 8; ++f) {
        int d = 128 * pw + 16 * f + q15;
        size_t base = ((size_t)(b * 4096 + qt * 64 + 16 * qf + 4 * g)) * 512 + d;
        f32x4 a = Oacc[qf][f];
        out[base]        = x[base]        + gam * a[0] * li0;
        out[base + 512]  = x[base + 512]  + gam * a[1] * li1;
        out[base + 1024] = x[base + 1024] + gam * a[2] * li2;
        out[base + 1536] = x[base + 1536] + gam * a[3] * li3;
      }
    }
  }
}

// ---------------- launch ----------------
extern "C" void kernel_launch(void* const* d_in, const int* in_sizes, int n_in,
                              void* d_out, int out_size, void* d_ws, size_t ws_size,
                              hipStream_t stream) {
  (void)in_sizes; (void)n_in; (void)out_size; (void)ws_size;
  const float* x  = (const float*)d_in[0];
  const float* Wq = (const float*)d_in[1];
  const float* bq = (const float*)d_in[2];
  const float* Wk = (const float*)d_in[3];
  const float* bk = (const float*)d_in[4];
  const float* gm = (const float*)d_in[5];
  float* out = (float*)d_out;

  char* ws = (char*)d_ws;   // ~68.2 MB
  unsigned short* Qb  = (unsigned short*)(ws);                // 16384*512 bf16
  unsigned short* Kb  = (unsigned short*)(ws + 16777216);     // 16384*512 bf16
  unsigned short* xT  = (unsigned short*)(ws + 33554432);     // 4*512*4096 bf16
  unsigned short* xb  = (unsigned short*)(ws + 50331648);     // 16384*512 bf16
  unsigned short* Wqb = (unsigned short*)(ws + 67108864);     // 512*512 bf16
  unsigned short* Wkb = (unsigned short*)(ws + 67633152);     // 512*512 bf16

  hipFuncSetAttribute((const void*)attn_kernel,
                      hipFuncAttributeMaxDynamicSharedMemorySize, 150272);

  cvt_w<<<512, 256, 0, stream>>>(Wq, Wk, Wqb, Wkb);
  prep_x<<<2048, 256, 0, stream>>>(x, xb, xT);
  proj_gemm<<<dim3(128, 4, 2), 256, 0, stream>>>(xb, Wqb, Wkb, bq, bk, Qb, Kb,
                                                 0.04419417382415922f);
  attn_kernel<<<256, 512, 150272, stream>>>(Qb, Kb, xT, x, gm, out);
}